// Round 2
// baseline (624.738 us; speedup 1.0000x reference)
//
#include <hip/hip_runtime.h>

// ---------- common ----------
typedef short sh8 __attribute__((ext_vector_type(8)));
typedef float f32x4 __attribute__((ext_vector_type(4)));

#define DEV __device__ __forceinline__

DEV f32x4 mfma16(sh8 a, sh8 b, f32x4 c) {
  return __builtin_amdgcn_mfma_f32_16x16x32_bf16(a, b, c, 0, 0, 0);
}

DEV unsigned short f2bf(float f) {
  unsigned u = __float_as_uint(f);
  u = u + 0x7FFFu + ((u >> 16) & 1u);   // RNE
  return (unsigned short)(u >> 16);
}

// ---------- kernel 1: x fp32 -> bf16 ----------
__global__ void cvt_x_kernel(const float* __restrict__ x, unsigned short* __restrict__ xb, int n4) {
  int i = blockIdx.x * blockDim.x + threadIdx.x;
  int stride = gridDim.x * blockDim.x;
  for (; i < n4; i += stride) {
    float4 v = ((const float4*)x)[i];
    ushort4 o;
    o.x = f2bf(v.x); o.y = f2bf(v.y); o.z = f2bf(v.z); o.w = f2bf(v.w);
    ((ushort4*)xb)[i] = o;
  }
}

// ---------- kernel 2: weight transpose + cvt (512x512 fp32 [K][N] -> bf16 [N][K]) ----------
__global__ void cvt_wT_kernel(const float* __restrict__ W0, const float* __restrict__ W1,
                              const float* __restrict__ W2, const float* __restrict__ W3,
                              unsigned short* __restrict__ T0, unsigned short* __restrict__ T1,
                              unsigned short* __restrict__ T2, unsigned short* __restrict__ T3) {
  const float* W; unsigned short* T;
  switch (blockIdx.z) {
    case 0: W = W0; T = T0; break;
    case 1: W = W1; T = T1; break;
    case 2: W = W2; T = T2; break;
    default: W = W3; T = T3; break;
  }
  __shared__ float tile[32][33];
  int tx = threadIdx.x & 31, ty = threadIdx.x >> 5;
  int r0 = blockIdx.y * 32, c0 = blockIdx.x * 32;
#pragma unroll
  for (int i = 0; i < 4; i++) tile[ty + i * 8][tx] = W[(r0 + ty + i * 8) * 512 + c0 + tx];
  __syncthreads();
#pragma unroll
  for (int i = 0; i < 4; i++) T[(c0 + ty + i * 8) * 512 + r0 + tx] = f2bf(tile[tx][ty + i * 8]);
}

// ---------- kernel 3: GEMM  C[M,512] = A[M,K]*Bt[512,K]^T + bias ----------
// 128x128 tile, BK=32, 4 waves (2x2), each wave 64x64 (4x4 frags of 16x16x32 MFMA)
template <bool BF16OUT>
__global__ __launch_bounds__(256, 2) void gemm_bt_kernel(
    const unsigned short* __restrict__ A,
    const unsigned short* __restrict__ Bt0, const unsigned short* __restrict__ Bt1,
    const unsigned short* __restrict__ Bt2,
    const float* __restrict__ b0, const float* __restrict__ b1, const float* __restrict__ b2,
    void* __restrict__ C0, void* __restrict__ C1, void* __restrict__ C2,
    int M, int K) {
  const unsigned short* Bt; const float* bias; void* Cv;
  switch (blockIdx.z) {
    case 0: Bt = Bt0; bias = b0; Cv = C0; break;
    case 1: Bt = Bt1; bias = b1; Cv = C1; break;
    default: Bt = Bt2; bias = b2; Cv = C2; break;
  }
  __shared__ __align__(16) unsigned short As[128 * 32];
  __shared__ __align__(16) unsigned short Bs[128 * 32];
  int tid = threadIdx.x;
  int lane = tid & 63, w = tid >> 6;
  int g = lane >> 4, r = lane & 15;
  int wr = w >> 1, wc = w & 1;
  int brow = blockIdx.x * 128, bcol = blockIdx.y * 128;
  f32x4 acc[4][4] = {};
  int nk = K >> 5;
  for (int ks = 0; ks < nk; ks++) {
#pragma unroll
    for (int cc = 0; cc < 2; cc++) {
      int c = tid + cc * 256;                  // 0..511
      int row = c >> 2, k8 = (c & 3) * 8;
      uint4 va = *(const uint4*)&A[(size_t)(brow + row) * K + ks * 32 + k8];
      uint4 vb = *(const uint4*)&Bt[(size_t)(bcol + row) * K + ks * 32 + k8];
      *(uint4*)&As[row * 32 + k8] = va;
      *(uint4*)&Bs[row * 32 + k8] = vb;
    }
    __syncthreads();
    sh8 af[4], bfr[4];
#pragma unroll
    for (int m = 0; m < 4; m++) af[m] = *(const sh8*)&As[(wr * 64 + m * 16 + r) * 32 + g * 8];
#pragma unroll
    for (int n = 0; n < 4; n++) bfr[n] = *(const sh8*)&Bs[(wc * 64 + n * 16 + r) * 32 + g * 8];
#pragma unroll
    for (int m = 0; m < 4; m++)
#pragma unroll
      for (int n = 0; n < 4; n++) acc[m][n] = mfma16(af[m], bfr[n], acc[m][n]);
    __syncthreads();
  }
#pragma unroll
  for (int n = 0; n < 4; n++) {
    int col = bcol + wc * 64 + n * 16 + r;
    float bv = bias[col];
#pragma unroll
    for (int m = 0; m < 4; m++) {
      int row = brow + wr * 64 + m * 16 + g * 4;
#pragma unroll
      for (int i = 0; i < 4; i++) {
        float v = acc[m][n][i] + bv;
        if (BF16OUT) ((unsigned short*)Cv)[(size_t)(row + i) * 512 + col] = f2bf(v);
        else         ((float*)Cv)[(size_t)(row + i) * 512 + col] = v;
      }
    }
  }
}

// ---------- kernel 4: v [8192][512] -> vT [512][8192] (bf16) ----------
__global__ void transpose_v_kernel(const unsigned short* __restrict__ in, unsigned short* __restrict__ out) {
  __shared__ unsigned short tile[32][33];
  int tx = threadIdx.x & 31, ty = threadIdx.x >> 5;
  int r0 = blockIdx.y * 32, c0 = blockIdx.x * 32;
#pragma unroll
  for (int i = 0; i < 4; i++) tile[ty + i * 8][tx] = in[(size_t)(r0 + ty + i * 8) * 512 + c0 + tx];
  __syncthreads();
#pragma unroll
  for (int i = 0; i < 4; i++) out[(size_t)(c0 + ty + i * 8) * 8192 + r0 + tx] = tile[tx][ty + i * 8];
}

// ---------- kernel 5: flash attention (KV-split=2) ----------
// grid 256 = 128 q-blocks x 2 splits; block 256 = 4 waves x 16 q-rows each.
// Per step (32 kv rows): QK^T (32 MFMA/wave) -> online softmax (exp2 domain,
// defer-max THR=4) -> P via per-wave LDS -> PV (32 MFMA/wave).
__global__ __launch_bounds__(256, 1) void flash_kernel(
    const unsigned short* __restrict__ Q,   // [8192][512] bf16
    const unsigned short* __restrict__ Kb,  // [8192][512] bf16
    const unsigned short* __restrict__ VT,  // [512][8192] bf16
    float* __restrict__ Pout,               // [2][8192][512] fp32 partials
    float* __restrict__ ML) {               // [2][2][8192] (m then l per split)
  constexpr int KST = 544;   // k_lds row stride (elems): 1088B, b128 reads ~conflict-free
  constexpr int VST = 40;    // vT_lds row stride: 80B, 16B-aligned
  constexpr int PST = 40;    // p_lds row stride
  __shared__ __align__(16) unsigned short k_lds[32 * KST];
  __shared__ __align__(16) unsigned short vT_lds[512 * VST];
  __shared__ __align__(16) unsigned short p_lds[4][16 * PST];

  int tid = threadIdx.x;
  int lane = tid & 63, w = tid >> 6;
  int g = lane >> 4, r = lane & 15;
  int qblk = blockIdx.x >> 1;
  int split = blockIdx.x & 1;
  int qbase = qblk * 64 + w * 16;

  // q fragments: full 512-d row per wave's 16 q-rows, 16 chunks of k=32
  sh8 qa[16];
#pragma unroll
  for (int dc = 0; dc < 16; dc++)
    qa[dc] = *(const sh8*)&Q[(size_t)(qbase + r) * 512 + dc * 32 + g * 8];

  f32x4 acc[32] = {};
  float mrow[4], lrow[4];
#pragma unroll
  for (int i = 0; i < 4; i++) { mrow[i] = -1e30f; lrow[i] = 0.f; }
  const float K2 = 0.04419417382415922f * 1.4426950408889634f;  // 1/sqrt(512)*log2(e)
  int kv0 = split * 4096;

  for (int s = 0; s < 128; s++) {
    int kvrow0 = kv0 + s * 32;
    {  // stage K tile [32][512] and vT tile [512][32]
      uint4 t[8];
#pragma unroll
      for (int cc = 0; cc < 8; cc++) {
        int c = tid + cc * 256;
        int row = c >> 6, d0 = (c & 63) * 8;
        t[cc] = *(const uint4*)&Kb[(size_t)(kvrow0 + row) * 512 + d0];
      }
#pragma unroll
      for (int cc = 0; cc < 8; cc++) {
        int c = tid + cc * 256;
        int row = c >> 6, d0 = (c & 63) * 8;
        *(uint4*)&k_lds[row * KST + d0] = t[cc];
      }
#pragma unroll
      for (int cc = 0; cc < 8; cc++) {
        int c = tid + cc * 256;
        int d = c >> 2, j0 = (c & 3) * 8;
        t[cc] = *(const uint4*)&VT[(size_t)d * 8192 + kvrow0 + j0];
      }
#pragma unroll
      for (int cc = 0; cc < 8; cc++) {
        int c = tid + cc * 256;
        int d = c >> 2, j0 = (c & 3) * 8;
        *(uint4*)&vT_lds[d * VST + j0] = t[cc];
      }
    }
    __syncthreads();

    // QK^T: S[16 q][32 j] as two 16x16 tiles
    f32x4 sA0 = {0.f, 0.f, 0.f, 0.f};
    f32x4 sA1 = {0.f, 0.f, 0.f, 0.f};
#pragma unroll
    for (int dc = 0; dc < 16; dc++) {
      sh8 k0 = *(const sh8*)&k_lds[r * KST + dc * 32 + g * 8];
      sh8 k1 = *(const sh8*)&k_lds[(16 + r) * KST + dc * 32 + g * 8];
      sA0 = mfma16(qa[dc], k0, sA0);
      sA1 = mfma16(qa[dc], k1, sA1);
    }

    // online softmax: lane holds rows 4g+i (i=0..3), col r (+16)
    float s0[4], s1[4], tmax[4];
    bool grow = false;
#pragma unroll
    for (int i = 0; i < 4; i++) {
      s0[i] = sA0[i] * K2;
      s1[i] = sA1[i] * K2;
      float t = fmaxf(s0[i], s1[i]);
      t = fmaxf(t, __shfl_xor(t, 1));
      t = fmaxf(t, __shfl_xor(t, 2));
      t = fmaxf(t, __shfl_xor(t, 4));
      t = fmaxf(t, __shfl_xor(t, 8));
      tmax[i] = t;
      grow = grow || (t > mrow[i] + 4.0f);
    }
    if (__any(grow)) {
#pragma unroll
      for (int i = 0; i < 4; i++) {
        float mn = fmaxf(mrow[i], tmax[i]);
        float corr = exp2f(mrow[i] - mn);
        lrow[i] *= corr;
        mrow[i] = mn;
#pragma unroll
        for (int dt = 0; dt < 32; dt++) acc[dt][i] *= corr;
      }
    }
#pragma unroll
    for (int i = 0; i < 4; i++) {
      float p0 = exp2f(s0[i] - mrow[i]);
      float p1 = exp2f(s1[i] - mrow[i]);
      p_lds[w][(4 * g + i) * PST + r] = f2bf(p0);
      p_lds[w][(4 * g + i) * PST + 16 + r] = f2bf(p1);
      float ps = p0 + p1;
      ps += __shfl_xor(ps, 1);
      ps += __shfl_xor(ps, 2);
      ps += __shfl_xor(ps, 4);
      ps += __shfl_xor(ps, 8);
      lrow[i] += ps;
    }

    // PV: acc[16 q][512 d] += P[16][32] * V[32][512]
    sh8 pf = *(const sh8*)&p_lds[w][r * PST + g * 8];
#pragma unroll
    for (int dt = 0; dt < 32; dt++) {
      sh8 vf = *(const sh8*)&vT_lds[(dt * 16 + r) * VST + g * 8];
      acc[dt] = mfma16(pf, vf, acc[dt]);
    }
    __syncthreads();
  }

  float* P = Pout + (size_t)split * 8192 * 512;
#pragma unroll
  for (int dt = 0; dt < 32; dt++) {
#pragma unroll
    for (int i = 0; i < 4; i++) {
      P[(size_t)(qbase + 4 * g + i) * 512 + dt * 16 + r] = acc[dt][i];
    }
  }
  if (r == 0) {
#pragma unroll
    for (int i = 0; i < 4; i++) {
      ML[(split * 2 + 0) * 8192 + qbase + 4 * g + i] = mrow[i];
      ML[(split * 2 + 1) * 8192 + qbase + 4 * g + i] = lrow[i];
    }
  }
}

// ---------- kernel 6: merge KV-split partials -> attended bf16 ----------
__global__ void combine_kernel(const float* __restrict__ Pp, const float* __restrict__ ML,
                               unsigned short* __restrict__ att) {
  int idx = blockIdx.x * blockDim.x + threadIdx.x;
  int stride = gridDim.x * blockDim.x;
  const float* P0 = Pp;
  const float* P1 = Pp + (size_t)8192 * 512;
  for (int i4 = idx; i4 < 8192 * 512 / 4; i4 += stride) {
    int row = i4 >> 7;
    float m1 = ML[row], l1 = ML[8192 + row];
    float m2 = ML[16384 + row], l2 = ML[24576 + row];
    float mm = fmaxf(m1, m2);
    float e1 = exp2f(m1 - mm), e2 = exp2f(m2 - mm);
    float inv = 1.0f / (l1 * e1 + l2 * e2);
    float4 a = ((const float4*)P0)[i4];
    float4 b = ((const float4*)P1)[i4];
    ushort4 o;
    o.x = f2bf((a.x * e1 + b.x * e2) * inv);
    o.y = f2bf((a.y * e1 + b.y * e2) * inv);
    o.z = f2bf((a.z * e1 + b.z * e2) * inv);
    o.w = f2bf((a.w * e1 + b.w * e2) * inv);
    ((ushort4*)att)[i4] = o;
  }
}

// ---------- launch ----------
extern "C" void kernel_launch(void* const* d_in, const int* in_sizes, int n_in,
                              void* d_out, int out_size, void* d_ws, size_t ws_size,
                              hipStream_t stream) {
  const float* x  = (const float*)d_in[0];
  const float* Wq = (const float*)d_in[1];
  const float* bq = (const float*)d_in[2];
  const float* Wk = (const float*)d_in[3];
  const float* bk = (const float*)d_in[4];
  const float* Wv = (const float*)d_in[5];
  const float* bv = (const float*)d_in[6];
  const float* Wo = (const float*)d_in[7];
  const float* bo = (const float*)d_in[8];

  char* ws = (char*)d_ws;
  unsigned short* xb  = (unsigned short*)(ws + 0);          //  8 MB
  unsigned short* qb  = (unsigned short*)(ws + 8388608);    //  8 MB
  unsigned short* kb  = (unsigned short*)(ws + 16777216);   //  8 MB
  unsigned short* vb  = (unsigned short*)(ws + 25165824);   //  8 MB
  unsigned short* vtb = (unsigned short*)(ws + 33554432);   //  8 MB
  unsigned short* att = (unsigned short*)(ws + 41943040);   //  8 MB
  unsigned short* wqT = (unsigned short*)(ws + 50331648);   // 0.5 MB
  unsigned short* wkT = (unsigned short*)(ws + 50855936);
  unsigned short* wvT = (unsigned short*)(ws + 51380224);
  unsigned short* woT = (unsigned short*)(ws + 51904512);
  float* part = (float*)(ws + 52428800);                    // 2 x 16 MB fp32
  float* ml   = (float*)(ws + 85983232);                    // 128 KB

  cvt_x_kernel<<<2048, 256, 0, stream>>>(x, xb, 8192 * 512 / 4);
  cvt_wT_kernel<<<dim3(16, 16, 4), 256, 0, stream>>>(Wq, Wk, Wv, Wo, wqT, wkT, wvT, woT);
  gemm_bt_kernel<true><<<dim3(64, 4, 3), 256, 0, stream>>>(
      xb, wqT, wkT, wvT, bq, bk, bv, qb, kb, vb, 8192, 512);
  transpose_v_kernel<<<dim3(16, 256), 256, 0, stream>>>(vb, vtb);
  flash_kernel<<<256, 256, 0, stream>>>(qb, kb, vtb, part, ml);
  combine_kernel<<<1024, 256, 0, stream>>>(part, ml, att);
  gemm_bt_kernel<false><<<dim3(64, 4, 1), 256, 0, stream>>>(
      att, woT, nullptr, nullptr, bo, nullptr, nullptr, (float*)d_out, nullptr, nullptr, 8192, 512);
}